// Round 5
// baseline (837.127 us; speedup 1.0000x reference)
//
#include <hip/hip_runtime.h>
#include <stdint.h>

// GateRow: out[b,g] = gates[g, 2*x[b,c0[g]] + x[b,c1[g]]]
// B=16384, N_IN=8192, N_GATES=8192.
// Harness canonicalizes bool -> int32 on device (confirmed round 4: output
// read back as int32; float 1.0f stores showed up as 1065353216).
// Output: int32 0/1, 512 MiB writes. x: int32 0/1, 536 MiB reads.
// A detection kernel still disambiguates int32 vs byte x-layout (cheap, safe).

static constexpr int BATCH  = 16384;
static constexpr int N_IN   = 8192;
static constexpr int NG     = 8192;
static constexpr int ROWS   = 8;     // batch rows bit-packed per block
static constexpr int BLK    = 256;
static constexpr int GPT    = 4;     // gates per thread per group (dwordx4 store)
static constexpr int NGROUP = NG / (BLK * GPT);   // 8

typedef uint32_t u32x4 __attribute__((ext_vector_type(4)));   // clang vector: OK for nontemporal builtins

// ---- Detect x element width: int32 (bytes 1..3 of each word == 0) vs u8 ----
__global__ void detect_mode(const uint8_t* __restrict__ x,
                            uint32_t* __restrict__ flag) {
    if (threadIdx.x == 0 && blockIdx.x == 0) {
        uint32_t nz = 0;
        for (int i = 0; i < 256; ++i)
            nz |= x[4 * i + 1] | x[4 * i + 2] | x[4 * i + 3];
        *flag = (nz == 0) ? 1u : 0u;   // 1 = int32 elements, 0 = byte elements
    }
}

// ---- Pack per-gate metadata: c0 | c1<<13 | truthtable<<26 ------------------
__global__ void pack_meta(const int* __restrict__ choices,
                          const void* __restrict__ gates_,
                          const uint32_t* __restrict__ flag,
                          uint32_t* __restrict__ meta) {
    int g = blockIdx.x * blockDim.x + threadIdx.x;
    if (g >= NG) return;
    uint32_t c0 = (uint32_t)choices[2 * g];
    uint32_t c1 = (uint32_t)choices[2 * g + 1];
    uint32_t tt;
    if (*flag) {
        const int* gt = (const int*)gates_;
        tt = ((uint32_t)gt[4 * g] & 1u)        | (((uint32_t)gt[4 * g + 1] & 1u) << 1)
           | (((uint32_t)gt[4 * g + 2] & 1u) << 2) | (((uint32_t)gt[4 * g + 3] & 1u) << 3);
    } else {
        const uint8_t* gt = (const uint8_t*)gates_;
        tt = (uint32_t)gt[4 * g]       | ((uint32_t)gt[4 * g + 1] << 1)
           | ((uint32_t)gt[4 * g + 2] << 2) | ((uint32_t)gt[4 * g + 3] << 3);
    }
    meta[g] = c0 | (c1 << 13) | (tt << 26);
}

template <bool PACKED>
__global__ __launch_bounds__(BLK) void gate_main(
        const void*     __restrict__ xv,
        const uint32_t* __restrict__ meta,
        const int*      __restrict__ choices,
        const void*     __restrict__ gates_,
        const uint32_t* __restrict__ flag,
        uint32_t*       __restrict__ out) {
    // xp[c] bit r == x[b0+r][c]  (8 rows bit-packed per byte)
    __shared__ uint8_t xp[N_IN];
    const int  t   = threadIdx.x;
    const long b0  = (long)blockIdx.x * ROWS;
    const bool i32 = flag ? (*flag != 0) : true;

    // ---- Stage: load 8 rows of x, bit-pack into LDS bytes ------------------
    if (i32) {
        const uint32_t* x = (const uint32_t*)xv;
        uint32_t* dst = (uint32_t*)xp;           // 4 packed bytes per store
        #pragma unroll
        for (int i = 0; i < N_IN / 4 / BLK; ++i) {   // 8 iterations
            const int o = t + i * BLK;                // 4-column group index
            uint32_t pb = 0;
            #pragma unroll
            for (int r = 0; r < ROWS; ++r) {
                const u32x4* src = (const u32x4*)(x + (b0 + r) * (long)N_IN) + o;
                u32x4 v = __builtin_nontemporal_load(src);
                pb |= (v.x << r) | (v.y << (r + 8))
                    | (v.z << (r + 16)) | (v.w << (r + 24));
            }
            dst[o] = pb;
        }
    } else {
        const u32x4* xr  = (const u32x4*)((const uint8_t*)xv + b0 * N_IN);
        u32x4*       dst = (u32x4*)xp;
        #pragma unroll
        for (int i = 0; i < N_IN / 16 / BLK; ++i) {  // 2 iterations
            const int o = t + i * BLK;                // 16-column group index
            u32x4 p = (u32x4){0u, 0u, 0u, 0u};
            #pragma unroll
            for (int r = 0; r < ROWS; ++r) {
                // bytes are 0/1 -> <<r stays within each byte lane (no carry)
                u32x4 v = __builtin_nontemporal_load(
                    &xr[(size_t)r * (N_IN / 16) + o]);
                p.x |= v.x << r;  p.y |= v.y << r;
                p.z |= v.z << r;  p.w |= v.w << r;
            }
            dst[o] = p;
        }
    }
    __syncthreads();

    // ---- Gate loop: 4 gates/thread/group, 8 rows each ----------------------
    for (int k = 0; k < NGROUP; ++k) {
        const int gbase = k * BLK * GPT + t * GPT;

        uint32_t mm[GPT];
        if (PACKED) {
            u32x4 m = ((const u32x4*)meta)[k * BLK + t];   // coalesced 16B
            mm[0] = m.x; mm[1] = m.y; mm[2] = m.z; mm[3] = m.w;
        } else {
            #pragma unroll
            for (int j = 0; j < GPT; ++j) {
                int g = gbase + j;
                uint32_t c0 = (uint32_t)choices[2 * g];
                uint32_t c1 = (uint32_t)choices[2 * g + 1];
                uint32_t tt;
                if (i32) {
                    const int* gt = (const int*)gates_;
                    tt = ((uint32_t)gt[4*g] & 1u)        | (((uint32_t)gt[4*g+1] & 1u) << 1)
                       | (((uint32_t)gt[4*g+2] & 1u) << 2) | (((uint32_t)gt[4*g+3] & 1u) << 3);
                } else {
                    const uint8_t* gt = (const uint8_t*)gates_;
                    tt = (uint32_t)gt[4*g] | ((uint32_t)gt[4*g+1] << 1)
                       | ((uint32_t)gt[4*g+2] << 2) | ((uint32_t)gt[4*g+3] << 3);
                }
                mm[j] = c0 | (c1 << 13) | (tt << 26);
            }
        }

        uint32_t res[ROWS][GPT];
        #pragma unroll
        for (int j = 0; j < GPT; ++j) {
            const uint32_t mv = mm[j];
            const uint32_t v0 = xp[mv & 8191u];           // 8 rows' chosen0 bits
            const uint32_t v1 = xp[(mv >> 13) & 8191u];   // 8 rows' chosen1 bits
            const uint32_t tt = mv >> 26;
            #pragma unroll
            for (int r = 0; r < ROWS; ++r) {
                const uint32_t idx = (((v0 >> r) & 1u) << 1) | ((v1 >> r) & 1u);
                res[r][j] = (tt >> idx) & 1u;             // int32 0/1 output
            }
        }

        #pragma unroll
        for (int r = 0; r < ROWS; ++r) {
            u32x4 v = { res[r][0], res[r][1], res[r][2], res[r][3] };
            u32x4* dst = (u32x4*)(out + (b0 + r) * (long)NG + gbase);
            __builtin_nontemporal_store(v, dst);   // streaming: out > L3
        }
    }
}

extern "C" void kernel_launch(void* const* d_in, const int* in_sizes, int n_in,
                              void* d_out, int out_size, void* d_ws, size_t ws_size,
                              hipStream_t stream) {
    const void* x       = d_in[0];
    const void* gates   = d_in[1];
    const int*  choices = (const int*)d_in[2];
    uint32_t*   out     = (uint32_t*)d_out;

    // ws layout: [0..3] mode flag, [64..64+32768) packed meta (16B-aligned)
    if (ws_size >= 64 + NG * sizeof(uint32_t)) {
        uint32_t* flag = (uint32_t*)d_ws;
        uint32_t* meta = (uint32_t*)((char*)d_ws + 64);
        detect_mode<<<1, 64, 0, stream>>>((const uint8_t*)x, flag);
        pack_meta<<<NG / BLK, BLK, 0, stream>>>(choices, gates, flag, meta);
        gate_main<true><<<BATCH / ROWS, BLK, 0, stream>>>(
            x, meta, choices, gates, flag, out);
    } else if (ws_size >= 4) {
        uint32_t* flag = (uint32_t*)d_ws;
        detect_mode<<<1, 64, 0, stream>>>((const uint8_t*)x, flag);
        gate_main<false><<<BATCH / ROWS, BLK, 0, stream>>>(
            x, nullptr, choices, gates, flag, out);
    } else {
        // no scratch at all: assume int32 elements (most likely layout)
        gate_main<false><<<BATCH / ROWS, BLK, 0, stream>>>(
            x, nullptr, choices, gates, nullptr, out);
    }
}

// Round 6
// 829.732 us; speedup vs baseline: 1.0089x; 1.0089x over previous
//
#include <hip/hip_runtime.h>
#include <stdint.h>

// GateRow: out[b,g] = gates[g, 2*x[b,c0[g]] + x[b,c1[g]]]
// B=16384, N_IN=8192, N_GATES=8192. Harness canonicalizes bool -> int32
// (confirmed r4/r5: output int32; input detection chose i32 and passed).
// HBM floor: read x 537 MB + write out 537 MB ~= 170 us @6.4 TB/s.
// Round 6: drop the serializing 1-thread detect kernel -> per-wave inline
// ballot detection; vectorize pack_meta; preload meta quads.

static constexpr int BATCH  = 16384;
static constexpr int N_IN   = 8192;
static constexpr int NG     = 8192;
static constexpr int ROWS   = 8;     // batch rows bit-packed per block
static constexpr int BLK    = 256;
static constexpr int GPT    = 4;     // gates per thread per group (dwordx4 store)
static constexpr int NGROUP = NG / (BLK * GPT);   // 8

typedef uint32_t u32x4 __attribute__((ext_vector_type(4)));
typedef int      i32x2 __attribute__((ext_vector_type(2)));

// int32-canonicalized bools => every 32-bit word is 0 or 1.
// Byte-bools => a word has upper-byte bits set w.p. 7/8 per word.
// Ballot over 64 lanes x 4 words => wrong verdict w.p. 2^-768. Wave-uniform.
__device__ __forceinline__ bool wave_detect_i32(u32x4 w) {
    return __ballot((((w.x | w.y | w.z | w.w) & ~1u) == 0u)) == ~0ULL;
}

// ---- Pack per-gate metadata: c0 | c1<<13 | truthtable<<26 ------------------
__global__ __launch_bounds__(BLK) void pack_meta(
        const int* __restrict__ choices,
        const void* __restrict__ gates_,
        uint32_t* __restrict__ meta) {
    const int g = blockIdx.x * BLK + threadIdx.x;   // 32 blocks x 256
    // Detect gates dtype from first 32 KB (in-bounds under BOTH layouts).
    const bool i32 = wave_detect_i32(((const u32x4*)gates_)[g & 2047]);
    i32x2 c = ((const i32x2*)choices)[g];
    uint32_t tt;
    if (i32) {
        u32x4 gw = ((const u32x4*)gates_)[g];       // gates[4g..4g+3] as int32
        tt = (gw.x & 1u) | ((gw.y & 1u) << 1)
           | ((gw.z & 1u) << 2) | ((gw.w & 1u) << 3);
    } else {
        const uint8_t* gt = (const uint8_t*)gates_ + 4 * (long)g;
        tt = (uint32_t)gt[0] | ((uint32_t)gt[1] << 1)
           | ((uint32_t)gt[2] << 2) | ((uint32_t)gt[3] << 3);
    }
    meta[g] = (uint32_t)c.x | ((uint32_t)c.y << 13) | (tt << 26);
}

template <bool PACKED>
__global__ __launch_bounds__(BLK) void gate_main(
        const void*     __restrict__ xv,
        const uint32_t* __restrict__ meta,
        const int*      __restrict__ choices,
        const void*     __restrict__ gates_,
        uint32_t*       __restrict__ out) {
    // xp[c] bit r == x[b0+r][c]  (8 rows bit-packed per byte)
    __shared__ uint8_t xp[N_IN];
    const int  t  = threadIdx.x;
    const long b0 = (long)blockIdx.x * ROWS;

    // Detect x dtype from the first 8.4 MB (in-bounds under BOTH layouts:
    // byte-mode buffer is 134 MB). One coalesced 16B load per thread.
    const bool i32 = wave_detect_i32(
        ((const u32x4*)xv)[blockIdx.x * BLK + t]);

    // ---- Stage: load 8 rows of x, bit-pack into LDS bytes ------------------
    if (i32) {
        const uint32_t* x = (const uint32_t*)xv;
        uint32_t* dst = (uint32_t*)xp;           // 4 packed bytes per store
        #pragma unroll
        for (int i = 0; i < N_IN / 4 / BLK; ++i) {   // 8 iterations
            const int o = t + i * BLK;                // 4-column group index
            uint32_t pb = 0;
            #pragma unroll
            for (int r = 0; r < ROWS; ++r) {
                const u32x4* src = (const u32x4*)(x + (b0 + r) * (long)N_IN) + o;
                u32x4 v = __builtin_nontemporal_load(src);
                pb |= (v.x << r) | (v.y << (r + 8))
                    | (v.z << (r + 16)) | (v.w << (r + 24));
            }
            dst[o] = pb;
        }
    } else {
        const u32x4* xr  = (const u32x4*)((const uint8_t*)xv + b0 * N_IN);
        u32x4*       dst = (u32x4*)xp;
        #pragma unroll
        for (int i = 0; i < N_IN / 16 / BLK; ++i) {  // 2 iterations
            const int o = t + i * BLK;                // 16-column group index
            u32x4 p = (u32x4){0u, 0u, 0u, 0u};
            #pragma unroll
            for (int r = 0; r < ROWS; ++r) {
                // bytes are 0/1 -> <<r stays within each byte lane (no carry)
                u32x4 v = __builtin_nontemporal_load(
                    &xr[(size_t)r * (N_IN / 16) + o]);
                p.x |= v.x << r;  p.y |= v.y << r;
                p.z |= v.z << r;  p.w |= v.w << r;
            }
            dst[o] = p;
        }
    }
    __syncthreads();

    // ---- Preload all meta quads (8 parallel L2 loads, static-indexed) ------
    u32x4 mq[NGROUP];
    if (PACKED) {
        #pragma unroll
        for (int k = 0; k < NGROUP; ++k)
            mq[k] = ((const u32x4*)meta)[k * BLK + t];
    } else {
        const bool gi32 = wave_detect_i32(
            ((const u32x4*)gates_)[(blockIdx.x * BLK + t) & 2047]);
        #pragma unroll
        for (int k = 0; k < NGROUP; ++k) {
            const int gb = k * BLK * GPT + t * GPT;
            #pragma unroll
            for (int j = 0; j < GPT; ++j) {
                const int g = gb + j;
                i32x2 c = ((const i32x2*)choices)[g];
                uint32_t tt;
                if (gi32) {
                    u32x4 gw = ((const u32x4*)gates_)[g];
                    tt = (gw.x & 1u) | ((gw.y & 1u) << 1)
                       | ((gw.z & 1u) << 2) | ((gw.w & 1u) << 3);
                } else {
                    const uint8_t* gt = (const uint8_t*)gates_ + 4 * (long)g;
                    tt = (uint32_t)gt[0] | ((uint32_t)gt[1] << 1)
                       | ((uint32_t)gt[2] << 2) | ((uint32_t)gt[3] << 3);
                }
                mq[k][j] = (uint32_t)c.x | ((uint32_t)c.y << 13) | (tt << 26);
            }
        }
    }

    // ---- Gate loop: 4 gates/thread/group, 8 rows each ----------------------
    #pragma unroll
    for (int k = 0; k < NGROUP; ++k) {
        const int gbase = k * BLK * GPT + t * GPT;

        uint32_t res[ROWS][GPT];
        #pragma unroll
        for (int j = 0; j < GPT; ++j) {
            const uint32_t mv = mq[k][j];
            const uint32_t v0 = xp[mv & 8191u];           // 8 rows' chosen0 bits
            const uint32_t v1 = xp[(mv >> 13) & 8191u];   // 8 rows' chosen1 bits
            const uint32_t tt = mv >> 26;
            #pragma unroll
            for (int r = 0; r < ROWS; ++r) {
                const uint32_t idx = (((v0 >> r) & 1u) << 1) | ((v1 >> r) & 1u);
                res[r][j] = (tt >> idx) & 1u;             // int32 0/1 output
            }
        }

        #pragma unroll
        for (int r = 0; r < ROWS; ++r) {
            u32x4 v = { res[r][0], res[r][1], res[r][2], res[r][3] };
            u32x4* dst = (u32x4*)(out + (b0 + r) * (long)NG + gbase);
            __builtin_nontemporal_store(v, dst);   // streaming: out > L3
        }
    }
}

extern "C" void kernel_launch(void* const* d_in, const int* in_sizes, int n_in,
                              void* d_out, int out_size, void* d_ws, size_t ws_size,
                              hipStream_t stream) {
    const void* x       = d_in[0];
    const void* gates   = d_in[1];
    const int*  choices = (const int*)d_in[2];
    uint32_t*   out     = (uint32_t*)d_out;

    if (ws_size >= NG * sizeof(uint32_t)) {
        uint32_t* meta = (uint32_t*)d_ws;
        pack_meta<<<NG / BLK, BLK, 0, stream>>>(choices, gates, meta);
        gate_main<true><<<BATCH / ROWS, BLK, 0, stream>>>(
            x, meta, choices, gates, out);
    } else {
        gate_main<false><<<BATCH / ROWS, BLK, 0, stream>>>(
            x, nullptr, choices, gates, out);
    }
}